// Round 2
// baseline (476.600 us; speedup 1.0000x reference)
//
#include <hip/hip_runtime.h>
#include <hip/hip_fp16.h>

// Problem constants (fixed by setup_inputs)
#define B_ 4096
#define D_ 256
#define N_ 8192           // 2*B
#define K_TOP 2047        // (N-2)/4
#define NBINS 2048
#define LISTCAP 256
#define RCPT 14.285714285714286f  // 1/0.07

typedef _Float16 half8 __attribute__((ext_vector_type(8)));
typedef _Float16 half4v __attribute__((ext_vector_type(4)));
typedef float floatx4 __attribute__((ext_vector_type(4)));

typedef unsigned int __attribute__((address_space(1))) guint_t;
typedef unsigned int __attribute__((address_space(3))) luint_t;

// ---------------- normalize: fp32 rows -> normalized fp16 ------------------
__global__ __launch_bounds__(256) void normalize_kernel(
    const float* __restrict__ ei, const float* __restrict__ ej,
    _Float16* __restrict__ E16, float* __restrict__ out) {
  if (blockIdx.x == 0 && threadIdx.x == 0) out[0] = 0.f;  // init accumulator
  int w = threadIdx.x >> 6, lane = threadIdx.x & 63;
  int row = blockIdx.x * 4 + w;
  const float* src = (row < B_) ? (ei + (size_t)row * D_)
                                : (ej + (size_t)(row - B_) * D_);
  float4 v = ((const float4*)src)[lane];  // 64 lanes x 4 floats = 256 = D
  float ss = v.x * v.x + v.y * v.y + v.z * v.z + v.w * v.w;
  #pragma unroll
  for (int off = 32; off > 0; off >>= 1) ss += __shfl_down(ss, off);
  ss = __shfl(ss, 0);
  float sc = 1.0f / fmaxf(sqrtf(ss), 1e-12f);
  half4v h; h[0] = (_Float16)(v.x * sc); h[1] = (_Float16)(v.y * sc);
  h[2] = (_Float16)(v.z * sc); h[3] = (_Float16)(v.w * sc);
  *(half4v*)(E16 + (size_t)row * D_ + lane * 4) = h;
}

// ---------------- S = (E E^T)/T fp16; m97-style global_load_lds staging ----
#define TS 128
#define BK 64
__global__ __launch_bounds__(256) void gemm_kernel(
    const _Float16* __restrict__ E, _Float16* __restrict__ S) {
  // unpadded rows (128 B); 16-B chunks XOR-swizzled by (row&7) for bank spread
  __shared__ __align__(16) _Float16 As[TS][BK];  // 16 KB
  __shared__ __align__(16) _Float16 Bs[TS][BK];  // 16 KB
  int bx = blockIdx.x;
  int tm = bx >> 6, tn = bx & 63;
  int m0 = tm * TS, n0 = tn * TS;
  int t = threadIdx.x, w = t >> 6, lane = t & 63;
  int quad = lane >> 4, l16 = lane & 15;
  int wr = (w & 1) * 64, wc = (w >> 1) * 64;
  int srow = lane >> 3;              // row within 8-row staging group
  int gch = (lane & 7) ^ srow;       // swizzled source chunk for this lane

  floatx4 zero = {0.f, 0.f, 0.f, 0.f};
  floatx4 acc[4][4];
  #pragma unroll
  for (int a = 0; a < 4; ++a)
    #pragma unroll
    for (int b = 0; b < 4; ++b) acc[a][b] = zero;

  for (int kb = 0; kb < D_; kb += BK) {
    __syncthreads();  // previous compute done reading LDS
    #pragma unroll
    for (int q = 0; q < 4; ++q) {
      int rbase = w * 32 + q * 8;          // wave-uniform
      int r = rbase + srow;
      const _Float16* sa = E + (size_t)(m0 + r) * D_ + kb + gch * 8;
      const _Float16* sb = E + (size_t)(n0 + r) * D_ + kb + gch * 8;
      __builtin_amdgcn_global_load_lds((const guint_t*)sa,
                                       (luint_t*)&As[rbase][0], 16, 0, 0);
      __builtin_amdgcn_global_load_lds((const guint_t*)sb,
                                       (luint_t*)&Bs[rbase][0], 16, 0, 0);
    }
    __syncthreads();  // drains vmcnt; staged data visible
    #pragma unroll
    for (int ks = 0; ks < BK; ks += 32) {
      int ks8 = ks >> 3;
      half8 aF[4], bF[4];
      #pragma unroll
      for (int ti = 0; ti < 4; ++ti) {
        int row = wr + ti * 16 + l16;
        int ch = (quad + ks8) ^ (l16 & 7);
        aF[ti] = *(const half8*)(&As[row][ch * 8]);
      }
      #pragma unroll
      for (int tj = 0; tj < 4; ++tj) {
        int row = wc + tj * 16 + l16;
        int ch = (quad + ks8) ^ (l16 & 7);
        bF[tj] = *(const half8*)(&Bs[row][ch * 8]);
      }
      #pragma unroll
      for (int ti = 0; ti < 4; ++ti)
        #pragma unroll
        for (int tj = 0; tj < 4; ++tj)
          acc[ti][tj] = __builtin_amdgcn_mfma_f32_16x16x32_f16(
              aF[ti], bF[tj], acc[ti][tj], 0, 0, 0);
    }
  }
  // C/D layout: col = lane&15, row = quad*4 + reg  (m89-verified, round-1 OK)
  #pragma unroll
  for (int ti = 0; ti < 4; ++ti)
    #pragma unroll
    for (int tj = 0; tj < 4; ++tj)
      #pragma unroll
      for (int rg = 0; rg < 4; ++rg) {
        int row = m0 + wr + ti * 16 + quad * 4 + rg;
        int col = n0 + wc + tj * 16 + l16;
        S[(size_t)row * N_ + col] = (_Float16)(acc[ti][tj][rg] * RCPT);
      }
}

// ---------------- per-row: register-resident histogram top-k + exp sums ----
__global__ __launch_bounds__(256) void row_kernel(
    const _Float16* __restrict__ S, const _Float16* __restrict__ E16,
    float* __restrict__ out) {
  __shared__ unsigned hist[NBINS];   // 8 KB
  __shared__ float hsum[NBINS];      // 8 KB: per-bin sum of exp(s)^2
  __shared__ float blist[LISTCAP];   // 1 KB boundary-bin values
  __shared__ unsigned sbuf[256];
  __shared__ float s_red[4];
  __shared__ unsigned s_bstar, s_nabove, s_cnt;
  int i = blockIdx.x, t = threadIdx.x;
  int posi = (i + B_) & (N_ - 1);

  for (int b = t; b < NBINS; b += 256) { hist[b] = 0u; hsum[b] = 0.f; }
  if (t == 0) s_cnt = 0u;

  // fused positive-pair dot (fp32 accumulate over fp16 inputs)
  float pd = (float)E16[(size_t)i * D_ + t] * (float)E16[(size_t)posi * D_ + t];
  #pragma unroll
  for (int off = 32; off > 0; off >>= 1) pd += __shfl_down(pd, off);
  if ((t & 63) == 0) s_red[t >> 6] = pd;

  // row -> registers: 4 coalesced half8 loads, 32 floats/thread
  float sv[32];
  {
    const half8* Sr = (const half8*)(S + (size_t)i * N_);
    #pragma unroll
    for (int j = 0; j < 4; ++j) {
      half8 hv = Sr[j * 256 + t];
      #pragma unroll
      for (int e = 0; e < 8; ++e) sv[j * 8 + e] = (float)hv[e];
    }
  }
  __syncthreads();
  float p_total = 0.f;
  if (t == 0) p_total = s_red[0] + s_red[1] + s_red[2] + s_red[3];

  const float lo = -14.5f;
  const float invw = (float)NBINS / 29.0f;
  int c0 = t * 8;

  // pass 1: histogram + sum of exp(s) + per-bin sum of exp(2s)
  float sum1 = 0.f;
  #pragma unroll
  for (int j = 0; j < 4; ++j)
    #pragma unroll
    for (int e = 0; e < 8; ++e) {
      int c = j * 2048 + c0 + e;
      float v = sv[j * 8 + e];
      int b = (int)((v - lo) * invw);
      b = max(0, min(NBINS - 1, b));
      if (c != i && c != posi) {
        float ex = __expf(v);
        sum1 += ex;
        atomicAdd(&hist[b], 1u);
        atomicAdd(&hsum[b], ex * ex);  // exp(2s)
      }
    }
  __syncthreads();

  // suffix scan over 256 chunks of 8 bins to locate K_TOP-th largest's bin
  unsigned cs = 0;
  #pragma unroll
  for (int q = 0; q < 8; ++q) cs += hist[t * 8 + q];
  sbuf[t] = cs;
  __syncthreads();
  for (int off = 1; off < 256; off <<= 1) {
    unsigned addv = (t + off < 256) ? sbuf[t + off] : 0u;
    __syncthreads();
    sbuf[t] += addv;
    __syncthreads();
  }
  unsigned incl = sbuf[t];        // count in chunks >= t
  unsigned above = incl - cs;     // count in chunks > t
  if (above < K_TOP && incl >= K_TOP) {  // exactly one thread
    unsigned cum = above;
    for (int b = t * 8 + 7; b >= t * 8; --b) {
      unsigned h = hist[b];
      if (cum + h >= K_TOP) { s_bstar = (unsigned)b; s_nabove = cum; break; }
      cum += h;
    }
  }
  __syncthreads();
  int bstar = (int)s_bstar;
  unsigned r = K_TOP - s_nabove;  // take r values from boundary bin

  // top-k sum from bins fully above threshold
  float sum2 = 0.f;
  for (int b = bstar + 1 + t; b < NBINS; b += 256) sum2 += hsum[b];

  // collect boundary-bin values (expected ~40)
  #pragma unroll
  for (int j = 0; j < 4; ++j)
    #pragma unroll
    for (int e = 0; e < 8; ++e) {
      int c = j * 2048 + c0 + e;
      float v = sv[j * 8 + e];
      int b = (int)((v - lo) * invw);
      b = max(0, min(NBINS - 1, b));
      if (b == bstar && c != i && c != posi) {
        unsigned idx = atomicAdd(&s_cnt, 1u);
        if (idx < LISTCAP) blist[idx] = v;
      }
    }
  __syncthreads();
  // exact rank selection among boundary values (ties -> equal exp, any order)
  unsigned cnt = s_cnt; if (cnt > LISTCAP) cnt = LISTCAP;
  for (unsigned e2 = t; e2 < cnt; e2 += 256) {
    float v = blist[e2];
    unsigned rank = 0;
    for (unsigned q = 0; q < cnt; ++q) {
      float u = blist[q];
      rank += (unsigned)((u > v) || (u == v && q < e2));
    }
    if (rank < r) { float ev = __expf(v); sum2 += ev * ev; }
  }

  // final block reduction and loss contribution
  float part = sum1 + sum2;
  #pragma unroll
  for (int off = 32; off > 0; off >>= 1) part += __shfl_down(part, off);
  __syncthreads();           // s_red reuse safe: all earlier reads done
  if ((t & 63) == 0) s_red[t >> 6] = part;
  __syncthreads();
  if (t == 0) {
    float tot = s_red[0] + s_red[1] + s_red[2] + s_red[3];
    float pi = p_total * RCPT;
    tot += __expf(pi);
    float loss = -pi + logf(tot);
    atomicAdd(out, loss * (1.0f / (float)N_));
  }
}

// ---------------- launch ---------------------------------------------------
extern "C" void kernel_launch(void* const* d_in, const int* in_sizes, int n_in,
                              void* d_out, int out_size, void* d_ws,
                              size_t ws_size, hipStream_t stream) {
  const float* ei = (const float*)d_in[0];
  const float* ej = (const float*)d_in[1];
  float* out = (float*)d_out;
  char* ws = (char*)d_ws;
  _Float16* S = (_Float16*)ws;                              // 134,217,728 B
  _Float16* E16 = (_Float16*)(ws + 134217728);              //   4,194,304 B

  normalize_kernel<<<N_ / 4, 256, 0, stream>>>(ei, ej, E16, out);
  gemm_kernel<<<(N_ / TS) * (N_ / TS), 256, 0, stream>>>(E16, S);
  row_kernel<<<N_, 256, 0, stream>>>(S, E16, out);
}